// Round 2
// baseline (312.311 us; speedup 1.0000x reference)
//
#include <hip/hip_runtime.h>

// CausalAttention: x[4,2048,1024] f32, Wq/Wk/Wv [1024,1024] f32 -> out [4,2048,1024] f32
// Pipeline: cvt x->bf16; cvt+transpose W->bf16; QKV bf16 MFMA GEMMs (m97 128^2 structure);
// scores = Q K^T -> fp16 (triangular blocks only); causal softmax in-place (fp16 -> bf16 P);
// O = P V via BT-GEMM against V^T (written transposed by QKV epilogue), K-loop causally limited.

using f32x4 = __attribute__((ext_vector_type(4))) float;
using s16x8 = __attribute__((ext_vector_type(8))) short;

#define CTX 2048
#define DIM 1024
#define NB 4

__device__ __forceinline__ short f2bf(float f) {
  union { float f; unsigned u; } v; v.f = f;
  unsigned r = (v.u + 0x7fffu + ((v.u >> 16) & 1u)) >> 16;
  return (short)r;
}

__device__ __forceinline__ void async16(const void* g, void* l) {
  __builtin_amdgcn_global_load_lds(
      (const __attribute__((address_space(1))) void*)g,
      (__attribute__((address_space(3))) void*)l, 16, 0, 0);
}

// ---------------- convert kernels ----------------

__global__ __launch_bounds__(256) void cvt_x(const float* __restrict__ in,
                                             short* __restrict__ out, long n8) {
  long i = (long)blockIdx.x * 256 + threadIdx.x;
  if (i >= n8) return;
  const float4* p = (const float4*)in;
  float4 a = p[i * 2], b = p[i * 2 + 1];
  short o[8];
  o[0] = f2bf(a.x); o[1] = f2bf(a.y); o[2] = f2bf(a.z); o[3] = f2bf(a.w);
  o[4] = f2bf(b.x); o[5] = f2bf(b.y); o[6] = f2bf(b.z); o[7] = f2bf(b.w);
  *(int4*)&out[i * 8] = *(int4*)o;
}

// W [1024][1024] f32 -> WT [1024 n][1024 k] bf16 (i.e. W^T), 3 matrices via z
__global__ __launch_bounds__(256) void cvt_wT(const float* __restrict__ Wq,
                                              const float* __restrict__ Wk,
                                              const float* __restrict__ Wv,
                                              short* __restrict__ WT) {
  int z = blockIdx.z;
  const float* W = (z == 0) ? Wq : (z == 1) ? Wk : Wv;
  short* o = WT + (long)z * DIM * DIM;
  __shared__ float t[32][33];
  int n0 = blockIdx.x * 32, k0 = blockIdx.y * 32;
  int tx = threadIdx.x, ty = threadIdx.y;  // block (32,8)
  #pragma unroll
  for (int j = 0; j < 4; ++j)
    t[ty + j * 8][tx] = W[(long)(k0 + ty + j * 8) * DIM + n0 + tx];
  __syncthreads();
  #pragma unroll
  for (int j = 0; j < 4; ++j)
    o[(long)(n0 + ty + j * 8) * DIM + k0 + tx] = f2bf(t[tx][ty + j * 8]);
}

// ---------------- GEMM (BT form): C[M,N] = A[M,K] * B[N,K]^T ----------------
// MODE: 0 = bf16 row-major, 1 = bf16 transposed (V^T[b][col][t], t = row&2047),
//       2 = fp16 row-major, 3 = f32 row-major
template <int MODE, bool CSKIP, bool KLIM>
__global__ __launch_bounds__(256) void gemm_bt(const short* __restrict__ A,
                                               const short* __restrict__ B,
                                               void* __restrict__ Cout,
                                               int M, int N, int K,
                                               long sA, long sB, long sC, int ldc) {
  const int bx = blockIdx.x, by = blockIdx.y, bz = blockIdx.z;
  if (CSKIP && by > bx) return;  // fully-masked causal block
  const short* Ab = A + bz * sA + (long)bx * 128 * K;
  const short* Bb = B + bz * sB + (long)by * 128 * K;
  __shared__ short As[128 * 32];
  __shared__ short Bs[128 * 32];
  const int tid = threadIdx.x;
  const int lane = tid & 63, wid = tid >> 6;
  const int wr = wid >> 1, wc = wid & 1;        // 2x2 wave grid, 64x64 per wave
  const int frow = lane & 15, kgrp = lane >> 4; // MFMA fragment indices

  f32x4 acc[4][4];
  const f32x4 zero = {0.f, 0.f, 0.f, 0.f};
  #pragma unroll
  for (int m = 0; m < 4; ++m)
    #pragma unroll
    for (int n = 0; n < 4; ++n) acc[m][n] = zero;

  int kt_end = K >> 5;
  if (KLIM) { int lim = (bx + 1) << 2; if (lim < kt_end) kt_end = lim; }

  const int e0 = wid * 512 + lane * 8;  // element offset in [128][32] tile

  for (int kt = 0; kt < kt_end; ++kt) {
    const int k0 = kt << 5;
    __syncthreads();  // previous tile's ds_reads done before overwrite
    #pragma unroll
    for (int p = 0; p < 2; ++p) {
      const int e = e0 + (p << 11);
      const int r = e >> 5, c = e & 31;
      async16(Ab + (long)r * K + (k0 + c), &As[e]);
      async16(Bb + (long)r * K + (k0 + c), &Bs[e]);
    }
    __syncthreads();  // compiler emits vmcnt(0) drain before barrier

    s16x8 af[4], bfr[4];
    #pragma unroll
    for (int m = 0; m < 4; ++m)
      af[m] = *(const s16x8*)&As[((wr << 6) + (m << 4) + frow) * 32 + (kgrp << 3)];
    #pragma unroll
    for (int n = 0; n < 4; ++n)
      bfr[n] = *(const s16x8*)&Bs[((wc << 6) + (n << 4) + frow) * 32 + (kgrp << 3)];
    #pragma unroll
    for (int m = 0; m < 4; ++m)
      #pragma unroll
      for (int n = 0; n < 4; ++n)
        acc[m][n] = __builtin_amdgcn_mfma_f32_16x16x32_bf16(af[m], bfr[n], acc[m][n], 0, 0, 0);
  }

  // epilogue: C/D layout col=lane&15, row=(lane>>4)*4+reg (m89-verified)
  const int row0 = (bx << 7) + (wr << 6);
  const int col0 = (by << 7) + (wc << 6);
  #pragma unroll
  for (int m = 0; m < 4; ++m) {
    #pragma unroll
    for (int n = 0; n < 4; ++n) {
      #pragma unroll
      for (int r = 0; r < 4; ++r) {
        const int row = row0 + (m << 4) + (kgrp << 2) + r;
        const int col = col0 + (n << 4) + frow;
        const float v = acc[m][n][r];
        if (MODE == 0) {
          ((short*)Cout)[bz * sC + (long)row * ldc + col] = f2bf(v);
        } else if (MODE == 1) {
          // V^T[b][col][t]: b = row>>11, t = row&2047
          const long off = (long)(row >> 11) * ((long)N * CTX) + (long)col * CTX + (row & (CTX - 1));
          ((short*)Cout)[off] = f2bf(v);
        } else if (MODE == 2) {
          ((_Float16*)Cout)[bz * sC + (long)row * ldc + col] = (_Float16)v;
        } else {
          ((float*)Cout)[bz * sC + (long)row * ldc + col] = v;
        }
      }
    }
  }
}

// ---------------- causal softmax, in place: S fp16 -> P bf16 ----------------
__global__ __launch_bounds__(256) void softmax_causal(void* __restrict__ Sbuf) {
  const int r = blockIdx.x, b = blockIdx.y;
  const long base = (long)b * CTX * CTX + (long)r * CTX;
  _Float16* S = (_Float16*)Sbuf + base;
  short* P = (short*)Sbuf + base;
  const int tid = threadIdx.x;
  const int lane = tid & 63, wid = tid >> 6;
  const int c0 = tid * 8;
  const float scale = 0.03125f;  // 1/sqrt(1024)

  _Float16 h[8];
  *(int4*)h = *(const int4*)&S[c0];
  float v[8];
  float m = -INFINITY;
  #pragma unroll
  for (int j = 0; j < 8; ++j) {
    v[j] = (c0 + j <= r) ? (float)h[j] * scale : -INFINITY;
    m = fmaxf(m, v[j]);
  }
  #pragma unroll
  for (int off = 32; off >= 1; off >>= 1) m = fmaxf(m, __shfl_xor(m, off));
  __shared__ float redm[4], reds[4];
  if (lane == 0) redm[wid] = m;
  __syncthreads();
  m = fmaxf(fmaxf(redm[0], redm[1]), fmaxf(redm[2], redm[3]));

  float p[8];
  float s = 0.f;
  #pragma unroll
  for (int j = 0; j < 8; ++j) {
    p[j] = exp2f((v[j] - m) * 1.44269504f);
    s += p[j];
  }
  #pragma unroll
  for (int off = 32; off >= 1; off >>= 1) s += __shfl_xor(s, off);
  if (lane == 0) reds[wid] = s;
  __syncthreads();
  s = reds[0] + reds[1] + reds[2] + reds[3];
  const float inv = 1.0f / s;

  short o[8];
  #pragma unroll
  for (int j = 0; j < 8; ++j) o[j] = f2bf(p[j] * inv);
  *(int4*)&P[c0] = *(int4*)o;
}

// ---------------- launch ----------------
extern "C" void kernel_launch(void* const* d_in, const int* in_sizes, int n_in,
                              void* d_out, int out_size, void* d_ws, size_t ws_size,
                              hipStream_t stream) {
  (void)in_sizes; (void)n_in; (void)out_size; (void)ws_size;
  const float* x  = (const float*)d_in[0];
  const float* Wq = (const float*)d_in[1];
  const float* Wk = (const float*)d_in[2];
  const float* Wv = (const float*)d_in[3];

  const long MB = 1024 * 1024;
  char* ws = (char*)d_ws;
  short* xb = (short*)(ws + 0);         // 16 MB  [8192][1024] bf16
  short* WT = (short*)(ws + 16 * MB);   //  6 MB  3x[1024 n][1024 k] bf16 (W^T)
  short* Qb = (short*)(ws + 24 * MB);   // 16 MB  [4][2048][1024] bf16
  short* Kb = (short*)(ws + 40 * MB);   // 16 MB
  short* Vt = (short*)(ws + 56 * MB);   // 16 MB  [4][1024 n][2048 t] bf16 (V^T)
  void*  S  = (void*)(ws + 72 * MB);    // 32 MB  [4][2048][2048] fp16 -> bf16 P in place

  // 1) x -> bf16
  cvt_x<<<4096, 256, 0, stream>>>(x, xb, (long)NB * CTX * DIM / 8);
  // 2) W -> W^T bf16 (3 matrices)
  cvt_wT<<<dim3(32, 32, 3), dim3(32, 8), 0, stream>>>(Wq, Wk, Wv, WT);
  // 3) Q,K = x @ Wq/Wk   (M=8192, N=1024, K=1024); Qb and Kb are adjacent: sC = 8M elems
  gemm_bt<0, false, false><<<dim3(64, 8, 2), 256, 0, stream>>>(
      xb, WT, Qb, NB * CTX, DIM, DIM, 0, (long)DIM * DIM, (long)NB * CTX * DIM, DIM);
  // 4) V^T = (x @ Wv)^T
  gemm_bt<1, false, false><<<dim3(64, 8, 1), 256, 0, stream>>>(
      xb, WT + 2L * DIM * DIM, Vt, NB * CTX, DIM, DIM, 0, 0, 0, DIM);
  // 5) S = Q K^T -> fp16, lower-triangular blocks only (M=N=2048, K=1024)
  gemm_bt<2, true, false><<<dim3(16, 16, NB), 256, 0, stream>>>(
      Qb, Kb, S, CTX, CTX, DIM, (long)CTX * DIM, (long)CTX * DIM, (long)CTX * CTX, CTX);
  // 6) causal softmax in place (fp16 scores -> bf16 P)
  softmax_causal<<<dim3(CTX, NB), 256, 0, stream>>>(S);
  // 7) O = P V  (M=2048, N=1024, K=2048), K-loop causally limited
  gemm_bt<3, false, true><<<dim3(16, 8, NB), 256, 0, stream>>>(
      (short*)S, Vt, d_out, CTX, DIM, CTX, (long)CTX * CTX, (long)DIM * CTX, (long)CTX * DIM, DIM);
}

// Round 3
// 284.952 us; speedup vs baseline: 1.0960x; 1.0960x over previous
//
#include <hip/hip_runtime.h>

// CausalAttention: x[4,2048,1024] f32, Wq/Wk/Wv [1024,1024] f32 -> out [4,2048,1024] f32
// Round 3: 2-phase double-buffered GEMM (T3-minimum recipe) + fused QKV projection.
// Pipeline: cvt x->bf16; cvt+transpose W->bf16 (stacked [3072][1024]);
// fused QKV GEMM (Q,K row-major; V written transposed); scores = Q K^T -> fp16
// (triangular blocks only); causal softmax in-place (fp16 -> bf16 P); O = P V^T-GEMM.

using f32x4 = __attribute__((ext_vector_type(4))) float;
using s16x8 = __attribute__((ext_vector_type(8))) short;

#define CTX 2048
#define DIM 1024
#define NB 4

__device__ __forceinline__ short f2bf(float f) {
  union { float f; unsigned u; } v; v.f = f;
  unsigned r = (v.u + 0x7fffu + ((v.u >> 16) & 1u)) >> 16;
  return (short)r;
}

__device__ __forceinline__ void async16(const void* g, void* l) {
  __builtin_amdgcn_global_load_lds(
      (const __attribute__((address_space(1))) void*)g,
      (__attribute__((address_space(3))) void*)l, 16, 0, 0);
}

// ---------------- convert kernels ----------------

__global__ __launch_bounds__(256) void cvt_x(const float* __restrict__ in,
                                             short* __restrict__ out, long n8) {
  long i = (long)blockIdx.x * 256 + threadIdx.x;
  if (i >= n8) return;
  const float4* p = (const float4*)in;
  float4 a = p[i * 2], b = p[i * 2 + 1];
  short o[8];
  o[0] = f2bf(a.x); o[1] = f2bf(a.y); o[2] = f2bf(a.z); o[3] = f2bf(a.w);
  o[4] = f2bf(b.x); o[5] = f2bf(b.y); o[6] = f2bf(b.z); o[7] = f2bf(b.w);
  *(int4*)&out[i * 8] = *(int4*)o;
}

// W [1024][1024] f32 -> WT [3072 rows][1024 k] bf16 (stacked Wq^T,Wk^T,Wv^T)
__global__ __launch_bounds__(256) void cvt_wT(const float* __restrict__ Wq,
                                              const float* __restrict__ Wk,
                                              const float* __restrict__ Wv,
                                              short* __restrict__ WT) {
  int z = blockIdx.z;
  const float* W = (z == 0) ? Wq : (z == 1) ? Wk : Wv;
  short* o = WT + (long)z * DIM * DIM;
  __shared__ float t[32][33];
  int n0 = blockIdx.x * 32, k0 = blockIdx.y * 32;
  int tx = threadIdx.x, ty = threadIdx.y;  // block (32,8)
  #pragma unroll
  for (int j = 0; j < 4; ++j)
    t[ty + j * 8][tx] = W[(long)(k0 + ty + j * 8) * DIM + n0 + tx];
  __syncthreads();
  #pragma unroll
  for (int j = 0; j < 4; ++j)
    o[(long)(n0 + ty + j * 8) * DIM + k0 + tx] = f2bf(t[tx][ty + j * 8]);
}

// ---------------- GEMM (BT form): C[M,N] = A[M,K] * B[N,K]^T ----------------
// 2-phase double-buffered (T3-minimum): STAGE(t+1) issued before compute(t),
// single vmcnt(0)+barrier per K-step.
// MODE: 2 = fp16 row-major, 3 = f32 row-major,
//       4 = fused QKV epilogue (col<1024 -> Q, <2048 -> K, else V^T[b][e][t])
template <int MODE, bool CSKIP, bool KLIM>
__global__ __launch_bounds__(256) void gemm_bt(const short* __restrict__ A,
                                               const short* __restrict__ B,
                                               void* __restrict__ Cout,
                                               int M, int N, int K,
                                               long sA, long sB, long sC, int ldc) {
  const int bx = blockIdx.x, by = blockIdx.y, bz = blockIdx.z;
  if (CSKIP && by > bx) return;  // fully-masked causal block
  const short* Ab = A + bz * sA + (long)bx * 128 * K;
  const short* Bb = B + bz * sB + (long)by * 128 * K;
  __shared__ short As[2][128 * 32];
  __shared__ short Bs[2][128 * 32];
  const int tid = threadIdx.x;
  const int lane = tid & 63, wid = tid >> 6;
  const int wr = wid >> 1, wc = wid & 1;        // 2x2 wave grid, 64x64 per wave
  const int frow = lane & 15, kgrp = lane >> 4; // MFMA fragment indices

  f32x4 acc[4][4];
  const f32x4 zero = {0.f, 0.f, 0.f, 0.f};
  #pragma unroll
  for (int m = 0; m < 4; ++m)
    #pragma unroll
    for (int n = 0; n < 4; ++n) acc[m][n] = zero;

  int kt_end = K >> 5;
  if (KLIM) { int lim = (bx + 1) << 2; if (lim < kt_end) kt_end = lim; }

  const int e0 = wid * 512 + lane * 8;  // element offset in [128][32] tile
  const int er = e0 >> 5, ec = e0 & 31;

  // prologue: stage tile 0 into buffer 0
  #pragma unroll
  for (int p = 0; p < 2; ++p) {
    const int e = e0 + (p << 11);
    const int r = er + (p << 6);
    async16(Ab + (long)r * K + ec, &As[0][e]);
    async16(Bb + (long)r * K + ec, &Bs[0][e]);
  }
  asm volatile("s_waitcnt vmcnt(0)");
  __syncthreads();

  int cur = 0;
  for (int kt = 0; kt < kt_end; ++kt) {
    // issue next tile's staging into the other buffer (overlaps with compute below)
    if (kt + 1 < kt_end) {
      const int k0n = (kt + 1) << 5;
      #pragma unroll
      for (int p = 0; p < 2; ++p) {
        const int e = e0 + (p << 11);
        const int r = er + (p << 6);
        async16(Ab + (long)r * K + (k0n + ec), &As[cur ^ 1][e]);
        async16(Bb + (long)r * K + (k0n + ec), &Bs[cur ^ 1][e]);
      }
    }

    s16x8 af[4], bfr[4];
    #pragma unroll
    for (int m = 0; m < 4; ++m)
      af[m] = *(const s16x8*)&As[cur][((wr << 6) + (m << 4) + frow) * 32 + (kgrp << 3)];
    #pragma unroll
    for (int n = 0; n < 4; ++n)
      bfr[n] = *(const s16x8*)&Bs[cur][((wc << 6) + (n << 4) + frow) * 32 + (kgrp << 3)];
    #pragma unroll
    for (int m = 0; m < 4; ++m)
      #pragma unroll
      for (int n = 0; n < 4; ++n)
        acc[m][n] = __builtin_amdgcn_mfma_f32_16x16x32_bf16(af[m], bfr[n], acc[m][n], 0, 0, 0);

    // next-tile loads complete + all waves done reading buf[cur]
    asm volatile("s_waitcnt vmcnt(0)");
    __syncthreads();
    cur ^= 1;
  }

  // epilogue: C/D layout col=lane&15, row=(lane>>4)*4+reg (m89-verified)
  const int row0 = (bx << 7) + (wr << 6);
  const int col0 = (by << 7) + (wc << 6);
  #pragma unroll
  for (int m = 0; m < 4; ++m) {
    #pragma unroll
    for (int n = 0; n < 4; ++n) {
      #pragma unroll
      for (int r = 0; r < 4; ++r) {
        const int row = row0 + (m << 4) + (kgrp << 2) + r;
        const int col = col0 + (n << 4) + frow;
        const float v = acc[m][n][r];
        if (MODE == 2) {
          ((_Float16*)Cout)[bz * sC + (long)row * ldc + col] = (_Float16)v;
        } else if (MODE == 3) {
          ((float*)Cout)[bz * sC + (long)row * ldc + col] = v;
        } else {  // MODE 4: fused QKV. row=(b,t); col<1024 Q, <2048 K, else V^T
          const long QK = (long)NB * CTX * DIM;
          long off;
          if (col < 2048) {
            off = (long)(col >> 10) * QK + (long)row * DIM + (col & 1023);
          } else {
            off = 2 * QK + (long)(row >> 11) * ((long)DIM * CTX) +
                  (long)(col - 2048) * CTX + (row & (CTX - 1));
          }
          ((short*)Cout)[off] = f2bf(v);
        }
      }
    }
  }
}

// ---------------- causal softmax, in place: S fp16 -> P bf16 ----------------
__global__ __launch_bounds__(256) void softmax_causal(void* __restrict__ Sbuf) {
  const int r = blockIdx.x, b = blockIdx.y;
  const long base = (long)b * CTX * CTX + (long)r * CTX;
  _Float16* S = (_Float16*)Sbuf + base;
  short* P = (short*)Sbuf + base;
  const int tid = threadIdx.x;
  const int lane = tid & 63, wid = tid >> 6;
  const int c0 = tid * 8;
  const float scale = 0.03125f;  // 1/sqrt(1024)

  _Float16 h[8];
  *(int4*)h = *(const int4*)&S[c0];
  float v[8];
  float m = -INFINITY;
  #pragma unroll
  for (int j = 0; j < 8; ++j) {
    v[j] = (c0 + j <= r) ? (float)h[j] * scale : -INFINITY;
    m = fmaxf(m, v[j]);
  }
  #pragma unroll
  for (int off = 32; off >= 1; off >>= 1) m = fmaxf(m, __shfl_xor(m, off));
  __shared__ float redm[4], reds[4];
  if (lane == 0) redm[wid] = m;
  __syncthreads();
  m = fmaxf(fmaxf(redm[0], redm[1]), fmaxf(redm[2], redm[3]));

  float p[8];
  float s = 0.f;
  #pragma unroll
  for (int j = 0; j < 8; ++j) {
    p[j] = exp2f((v[j] - m) * 1.44269504f);
    s += p[j];
  }
  #pragma unroll
  for (int off = 32; off >= 1; off >>= 1) s += __shfl_xor(s, off);
  if (lane == 0) reds[wid] = s;
  __syncthreads();
  s = reds[0] + reds[1] + reds[2] + reds[3];
  const float inv = 1.0f / s;

  short o[8];
  #pragma unroll
  for (int j = 0; j < 8; ++j) o[j] = f2bf(p[j] * inv);
  *(int4*)&P[c0] = *(int4*)o;
}

// ---------------- launch ----------------
extern "C" void kernel_launch(void* const* d_in, const int* in_sizes, int n_in,
                              void* d_out, int out_size, void* d_ws, size_t ws_size,
                              hipStream_t stream) {
  (void)in_sizes; (void)n_in; (void)out_size; (void)ws_size;
  const float* x  = (const float*)d_in[0];
  const float* Wq = (const float*)d_in[1];
  const float* Wk = (const float*)d_in[2];
  const float* Wv = (const float*)d_in[3];

  const long MB = 1024 * 1024;
  char* ws = (char*)d_ws;
  short* xb = (short*)(ws + 0);         // 16 MB  [8192][1024] bf16
  short* WT = (short*)(ws + 16 * MB);   //  6 MB  [3072][1024] bf16 (Wq^T,Wk^T,Wv^T stacked)
  short* Qb = (short*)(ws + 24 * MB);   // 16 MB  [4][2048][1024] bf16
  short* Kb = (short*)(ws + 40 * MB);   // 16 MB  (contiguous after Qb)
  short* Vt = (short*)(ws + 56 * MB);   // 16 MB  [4][1024 e][2048 t] bf16 (V^T, after Kb)
  void*  S  = (void*)(ws + 72 * MB);    // 32 MB  [4][2048][2048] fp16 -> bf16 P in place

  // 1) x -> bf16
  cvt_x<<<4096, 256, 0, stream>>>(x, xb, (long)NB * CTX * DIM / 8);
  // 2) W -> W^T bf16 (3 matrices, stacked)
  cvt_wT<<<dim3(32, 32, 3), dim3(32, 8), 0, stream>>>(Wq, Wk, Wv, WT);
  // 3) fused QKV: [8192,1024] @ [3072,1024]^T; epilogue routes Q/K row-major, V transposed
  gemm_bt<4, false, false><<<dim3(64, 24, 1), 256, 0, stream>>>(
      xb, WT, Qb, NB * CTX, 3 * DIM, DIM, 0, 0, 0, DIM);
  // 4) S = Q K^T -> fp16, lower-triangular blocks only (M=N=2048, K=1024)
  gemm_bt<2, true, false><<<dim3(16, 16, NB), 256, 0, stream>>>(
      Qb, Kb, S, CTX, CTX, DIM, (long)CTX * DIM, (long)CTX * DIM, (long)CTX * CTX, CTX);
  // 5) causal softmax in place (fp16 scores -> bf16 P)
  softmax_causal<<<dim3(CTX, NB), 256, 0, stream>>>(S);
  // 6) O = P V  (M=2048, N=1024, K=2048), K-loop causally limited
  gemm_bt<3, false, true><<<dim3(16, 8, NB), 256, 0, stream>>>(
      (short*)S, Vt, d_out, CTX, DIM, CTX, (long)CTX * CTX, (long)DIM * CTX, (long)CTX * DIM, DIM);
}

// Round 4
// 284.941 us; speedup vs baseline: 1.0961x; 1.0000x over previous
//
#include <hip/hip_runtime.h>

// CausalAttention: x[4,2048,1024] f32, Wq/Wk/Wv [1024,1024] f32 -> out [4,2048,1024] f32
// Round 4: depth-3 counted-vmcnt GEMM pipeline (T4): 3 LDS buffers, stage(t+2),
// wait vmcnt(4) + RAW s_barrier (no __syncthreads drain). Fused QKV projection;
// causal-skip scores; softmax with causal load/store trimming; PV with descending-bx.

using f32x4 = __attribute__((ext_vector_type(4))) float;
using s16x8 = __attribute__((ext_vector_type(8))) short;

#define CTX 2048
#define DIM 1024
#define NB 4

__device__ __forceinline__ short f2bf(float f) {
  union { float f; unsigned u; } v; v.f = f;
  unsigned r = (v.u + 0x7fffu + ((v.u >> 16) & 1u)) >> 16;
  return (short)r;
}

__device__ __forceinline__ void async16(const void* g, void* l) {
  __builtin_amdgcn_global_load_lds(
      (const __attribute__((address_space(1))) void*)g,
      (__attribute__((address_space(3))) void*)l, 16, 0, 0);
}

// ---------------- convert kernels ----------------

__global__ __launch_bounds__(256) void cvt_x(const float* __restrict__ in,
                                             short* __restrict__ out, long n8) {
  long i = (long)blockIdx.x * 256 + threadIdx.x;
  if (i >= n8) return;
  const float4* p = (const float4*)in;
  float4 a = p[i * 2], b = p[i * 2 + 1];
  short o[8];
  o[0] = f2bf(a.x); o[1] = f2bf(a.y); o[2] = f2bf(a.z); o[3] = f2bf(a.w);
  o[4] = f2bf(b.x); o[5] = f2bf(b.y); o[6] = f2bf(b.z); o[7] = f2bf(b.w);
  *(int4*)&out[i * 8] = *(int4*)o;
}

// W [1024][1024] f32 -> WT [3072 rows][1024 k] bf16 (stacked Wq^T,Wk^T,Wv^T)
__global__ __launch_bounds__(256) void cvt_wT(const float* __restrict__ Wq,
                                              const float* __restrict__ Wk,
                                              const float* __restrict__ Wv,
                                              short* __restrict__ WT) {
  int z = blockIdx.z;
  const float* W = (z == 0) ? Wq : (z == 1) ? Wk : Wv;
  short* o = WT + (long)z * DIM * DIM;
  __shared__ float t[32][33];
  int n0 = blockIdx.x * 32, k0 = blockIdx.y * 32;
  int tx = threadIdx.x, ty = threadIdx.y;  // block (32,8)
  #pragma unroll
  for (int j = 0; j < 4; ++j)
    t[ty + j * 8][tx] = W[(long)(k0 + ty + j * 8) * DIM + n0 + tx];
  __syncthreads();
  #pragma unroll
  for (int j = 0; j < 4; ++j)
    o[(long)(n0 + ty + j * 8) * DIM + k0 + tx] = f2bf(t[tx][ty + j * 8]);
}

// ---------------- GEMM (BT form): C[M,N] = A[M,K] * B[N,K]^T ----------------
// Depth-3 pipeline: buffers rotate kt%3; iteration kt waits vmcnt(4)
// (tile kt's 4 loads done, tile kt+1's 4 in flight), raw s_barrier,
// stages tile kt+2, then ds_read+MFMA tile kt. No vmcnt(0) in steady state.
// MODE: 2 = fp16 row-major, 3 = f32 row-major,
//       4 = fused QKV epilogue (col<1024 -> Q, <2048 -> K, else V^T[b][e][t])
template <int MODE, bool CSKIP, bool KLIM>
__global__ __launch_bounds__(256) void gemm_bt(const short* __restrict__ A,
                                               const short* __restrict__ B,
                                               void* __restrict__ Cout,
                                               int M, int N, int K,
                                               long sA, long sB, long sC, int ldc) {
  // KLIM (PV): descending bx so heavy blocks (long K-loops) dispatch first
  const int bx = KLIM ? ((int)gridDim.x - 1 - (int)blockIdx.x) : (int)blockIdx.x;
  const int by = blockIdx.y, bz = blockIdx.z;
  if (CSKIP && by > bx) return;  // fully-masked causal block
  const short* Ab = A + bz * sA + (long)bx * 128 * K;
  const short* Bb = B + bz * sB + (long)by * 128 * K;
  __shared__ short As[3][128 * 32];
  __shared__ short Bs[3][128 * 32];
  const int tid = threadIdx.x;
  const int lane = tid & 63, wid = tid >> 6;
  const int wr = wid >> 1, wc = wid & 1;        // 2x2 wave grid, 64x64 per wave
  const int frow = lane & 15, kgrp = lane >> 4; // MFMA fragment indices

  f32x4 acc[4][4];
  const f32x4 zero = {0.f, 0.f, 0.f, 0.f};
  #pragma unroll
  for (int m = 0; m < 4; ++m)
    #pragma unroll
    for (int n = 0; n < 4; ++n) acc[m][n] = zero;

  int kt_end = K >> 5;
  if (KLIM) { int lim = (bx + 1) << 2; if (lim < kt_end) kt_end = lim; }
  // kt_end >= 4 for all our launches

  const int e0 = wid * 512 + lane * 8;  // element offset in [128][32] tile
  const int er = e0 >> 5, ec = e0 & 31;

  // prologue: stage tiles 0 and 1 into buffers 0 and 1 (8 loads in flight)
  #pragma unroll
  for (int t = 0; t < 2; ++t) {
    const int k0 = t << 5;
    #pragma unroll
    for (int p = 0; p < 2; ++p) {
      const int e = e0 + (p << 11);
      const int r = er + (p << 6);
      async16(Ab + (long)r * K + (k0 + ec), &As[t][e]);
      async16(Bb + (long)r * K + (k0 + ec), &Bs[t][e]);
    }
  }

  int cur = 0, stg = 2;
  for (int kt = 0; kt < kt_end; ++kt) {
    // tile kt's loads (oldest 4) complete; tile kt+1's may stay in flight
    if (kt + 1 < kt_end) asm volatile("s_waitcnt vmcnt(4)" ::: "memory");
    else                 asm volatile("s_waitcnt vmcnt(0)" ::: "memory");
    __builtin_amdgcn_s_barrier();   // raw barrier: no implicit drain
    asm volatile("" ::: "memory");  // fence compiler motion of LDS reads

    // stage tile kt+2 into the buffer consumed at iter kt-1 (all waves past barrier)
    if (kt + 2 < kt_end) {
      const int k0n = (kt + 2) << 5;
      #pragma unroll
      for (int p = 0; p < 2; ++p) {
        const int e = e0 + (p << 11);
        const int r = er + (p << 6);
        async16(Ab + (long)r * K + (k0n + ec), &As[stg][e]);
        async16(Bb + (long)r * K + (k0n + ec), &Bs[stg][e]);
      }
    }

    s16x8 af[4], bfr[4];
    #pragma unroll
    for (int m = 0; m < 4; ++m)
      af[m] = *(const s16x8*)&As[cur][((wr << 6) + (m << 4) + frow) * 32 + (kgrp << 3)];
    #pragma unroll
    for (int n = 0; n < 4; ++n)
      bfr[n] = *(const s16x8*)&Bs[cur][((wc << 6) + (n << 4) + frow) * 32 + (kgrp << 3)];
    #pragma unroll
    for (int m = 0; m < 4; ++m)
      #pragma unroll
      for (int n = 0; n < 4; ++n)
        acc[m][n] = __builtin_amdgcn_mfma_f32_16x16x32_bf16(af[m], bfr[n], acc[m][n], 0, 0, 0);

    cur = (cur == 2) ? 0 : cur + 1;
    stg = (stg == 2) ? 0 : stg + 1;
  }

  // epilogue: C/D layout col=lane&15, row=(lane>>4)*4+reg (m89-verified)
  const int row0 = (bx << 7) + (wr << 6);
  const int col0 = (by << 7) + (wc << 6);
  #pragma unroll
  for (int m = 0; m < 4; ++m) {
    #pragma unroll
    for (int n = 0; n < 4; ++n) {
      #pragma unroll
      for (int r = 0; r < 4; ++r) {
        const int row = row0 + (m << 4) + (kgrp << 2) + r;
        const int col = col0 + (n << 4) + frow;
        const float v = acc[m][n][r];
        if (MODE == 2) {
          ((_Float16*)Cout)[bz * sC + (long)row * ldc + col] = (_Float16)v;
        } else if (MODE == 3) {
          ((float*)Cout)[bz * sC + (long)row * ldc + col] = v;
        } else {  // MODE 4: fused QKV. row=(b,t); col<1024 Q, <2048 K, else V^T
          const long QK = (long)NB * CTX * DIM;
          long off;
          if (col < 2048) {
            off = (long)(col >> 10) * QK + (long)row * DIM + (col & 1023);
          } else {
            off = 2 * QK + (long)(row >> 11) * ((long)DIM * CTX) +
                  (long)(col - 2048) * CTX + (row & (CTX - 1));
          }
          ((short*)Cout)[off] = f2bf(v);
        }
      }
    }
  }
}

// ---------------- causal softmax, in place: S fp16 -> P bf16 ----------------
// Trims loads past the causal column and stores past the 128-block boundary
// (PV reads exactly cols [0, ((r>>7)+1)*128), all written).
__global__ __launch_bounds__(256) void softmax_causal(void* __restrict__ Sbuf) {
  const int r = blockIdx.x, b = blockIdx.y;
  const long base = (long)b * CTX * CTX + (long)r * CTX;
  _Float16* S = (_Float16*)Sbuf + base;
  short* P = (short*)Sbuf + base;
  const int tid = threadIdx.x;
  const int lane = tid & 63, wid = tid >> 6;
  const int c0 = tid * 8;
  const int ncol = ((r >> 7) + 1) << 7;  // causal block boundary
  const float scale = 0.03125f;  // 1/sqrt(1024)

  float v[8];
  if (c0 <= r) {
    _Float16 h[8];
    *(int4*)h = *(const int4*)&S[c0];
    #pragma unroll
    for (int j = 0; j < 8; ++j)
      v[j] = (c0 + j <= r) ? (float)h[j] * scale : -INFINITY;
  } else {
    #pragma unroll
    for (int j = 0; j < 8; ++j) v[j] = -INFINITY;
  }
  float m = -INFINITY;
  #pragma unroll
  for (int j = 0; j < 8; ++j) m = fmaxf(m, v[j]);
  #pragma unroll
  for (int off = 32; off >= 1; off >>= 1) m = fmaxf(m, __shfl_xor(m, off));
  __shared__ float redm[4], reds[4];
  if (lane == 0) redm[wid] = m;
  __syncthreads();
  m = fmaxf(fmaxf(redm[0], redm[1]), fmaxf(redm[2], redm[3]));

  float p[8];
  float s = 0.f;
  #pragma unroll
  for (int j = 0; j < 8; ++j) {
    p[j] = exp2f((v[j] - m) * 1.44269504f);
    s += p[j];
  }
  #pragma unroll
  for (int off = 32; off >= 1; off >>= 1) s += __shfl_xor(s, off);
  if (lane == 0) reds[wid] = s;
  __syncthreads();
  s = reds[0] + reds[1] + reds[2] + reds[3];
  const float inv = 1.0f / s;

  if (c0 < ncol) {
    short o[8];
    #pragma unroll
    for (int j = 0; j < 8; ++j) o[j] = f2bf(p[j] * inv);
    *(int4*)&P[c0] = *(int4*)o;
  }
}

// ---------------- launch ----------------
extern "C" void kernel_launch(void* const* d_in, const int* in_sizes, int n_in,
                              void* d_out, int out_size, void* d_ws, size_t ws_size,
                              hipStream_t stream) {
  (void)in_sizes; (void)n_in; (void)out_size; (void)ws_size;
  const float* x  = (const float*)d_in[0];
  const float* Wq = (const float*)d_in[1];
  const float* Wk = (const float*)d_in[2];
  const float* Wv = (const float*)d_in[3];

  const long MB = 1024 * 1024;
  char* ws = (char*)d_ws;
  short* xb = (short*)(ws + 0);         // 16 MB  [8192][1024] bf16
  short* WT = (short*)(ws + 16 * MB);   //  6 MB  [3072][1024] bf16 (Wq^T,Wk^T,Wv^T stacked)
  short* Qb = (short*)(ws + 24 * MB);   // 16 MB  [4][2048][1024] bf16
  short* Kb = (short*)(ws + 40 * MB);   // 16 MB  (contiguous after Qb)
  short* Vt = (short*)(ws + 56 * MB);   // 16 MB  [4][1024 e][2048 t] bf16 (V^T, after Kb)
  void*  S  = (void*)(ws + 72 * MB);    // 32 MB  [4][2048][2048] fp16 -> bf16 P in place

  // 1) x -> bf16
  cvt_x<<<4096, 256, 0, stream>>>(x, xb, (long)NB * CTX * DIM / 8);
  // 2) W -> W^T bf16 (3 matrices, stacked)
  cvt_wT<<<dim3(32, 32, 3), dim3(32, 8), 0, stream>>>(Wq, Wk, Wv, WT);
  // 3) fused QKV: [8192,1024] @ [3072,1024]^T; epilogue routes Q/K row-major, V transposed
  gemm_bt<4, false, false><<<dim3(64, 24, 1), 256, 0, stream>>>(
      xb, WT, Qb, NB * CTX, 3 * DIM, DIM, 0, 0, 0, DIM);
  // 4) S = Q K^T -> fp16, lower-triangular blocks only (M=N=2048, K=1024)
  gemm_bt<2, true, false><<<dim3(16, 16, NB), 256, 0, stream>>>(
      Qb, Kb, S, CTX, CTX, DIM, (long)CTX * DIM, (long)CTX * DIM, (long)CTX * CTX, CTX);
  // 5) causal softmax in place (fp16 scores -> bf16 P)
  softmax_causal<<<dim3(CTX, NB), 256, 0, stream>>>(S);
  // 6) O = P V  (M=2048, N=1024, K=2048), K-loop causally limited, heavy blocks first
  gemm_bt<3, false, true><<<dim3(16, 8, NB), 256, 0, stream>>>(
      (short*)S, Vt, d_out, CTX, DIM, CTX, (long)CTX * CTX, (long)DIM * CTX, (long)CTX * DIM, DIM);
}